// Round 1
// 123.960 us; speedup vs baseline: 1.0162x; 1.0162x over previous
//
#include <hip/hip_runtime.h>

#define BATCH 4
#define NPTS 16384
#define NQ 2048
#define NFEAT 64
#define NS 32
#define NCH 67        // 3 + NFEAT
#define GRID 10       // cell edge 0.1 == radius
#define NCELL 1000
#define CSTRIDE 1024  // per-batch stride for cellStart
#define MAXHIT 128    // hit-list capacity per query (expected ~58 hits)

__device__ __forceinline__ int prefix_popc(unsigned long long m) {
  return (int)__builtin_amdgcn_mbcnt_hi(
      (unsigned)(m >> 32), __builtin_amdgcn_mbcnt_lo((unsigned)m, 0u));
}

// Wave-local LDS fence: all shared arrays in qg_main are per-wave, so
// cross-lane LDS visibility within the lockstep wave64 only needs the LDS
// queue drained. "memory" clobber stops compiler reordering of LDS accesses.
__device__ __forceinline__ void wave_fence() {
  asm volatile("s_waitcnt lgkmcnt(0)" ::: "memory");
}

__device__ __forceinline__ void cell3(float x, float y, float z, int& cx,
                                      int& cy, int& cz) {
  cx = min(max((int)(x * 10.0f), 0), GRID - 1);
  cy = min(max((int)(y * 10.0f), 0), GRID - 1);
  cz = min(max((int)(z * 10.0f), 0), GRID - 1);
}

// ---------------------------------------------------------------------------
// prep: blocks 0..3 build the per-batch cell grid in LDS; blocks 4.. transpose
// (B,C,N)->(B,N,C).  Change vs previous round: the 1024-wide Hillis-Steele
// scan (20 syncthreads) is replaced by a shfl-based wave scan + 16-entry
// cross-wave scan (3 syncthreads) — this block gates qg_main's start.
// ---------------------------------------------------------------------------
__global__ __launch_bounds__(1024) void prep_kernel(
    const float* __restrict__ xyz, const float* __restrict__ feat,
    float* __restrict__ featT, float4* __restrict__ cellPts,
    int* __restrict__ cellStart) {
  __shared__ float4 smem[64 * 65 / 4];  // 16.6 KB shared by both roles
  int* lhist = (int*)smem;              // [1024]
  int* lwsum = lhist + 1024;            // [16] wave partial sums
  int* lfill = lhist + 2048;            // [1024]
  float(*tile)[65] = (float(*)[65])smem;
  const int tid = threadIdx.x;

  if (blockIdx.x < BATCH) {
    const int b = blockIdx.x;
    const float* xb = xyz + (size_t)b * NPTS * 3;
    lhist[tid] = 0;
    lfill[tid] = 0;
    __syncthreads();
#pragma unroll
    for (int c = 0; c < NPTS / 1024; c++) {
      const int i = c * 1024 + tid;
      const float x = xb[i * 3 + 0];
      const float y = xb[i * 3 + 1];
      const float z = xb[i * 3 + 2];
      int cx, cy, cz;
      cell3(x, y, z, cx, cy, cz);
      atomicAdd(&lhist[(cz * GRID + cy) * GRID + cx], 1);
    }
    __syncthreads();
    const int val = lhist[tid];
    const int wid = tid >> 6;
    const int lane = tid & 63;
    // wave-level inclusive scan in registers
    int incl = val;
#pragma unroll
    for (int d = 1; d < 64; d <<= 1) {
      const int t = __shfl_up(incl, d);
      if (lane >= d) incl += t;
    }
    if (lane == 63) lwsum[wid] = incl;
    __syncthreads();
    if (wid == 0 && lane < 16) {
      const int ws = lwsum[lane];
      int wincl = ws;
#pragma unroll
      for (int d = 1; d < 16; d <<= 1) {
        const int t = __shfl_up(wincl, d);
        if (lane >= d) wincl += t;
      }
      lwsum[lane] = wincl - ws;  // exclusive wave offset
    }
    __syncthreads();
    const int excl = lwsum[wid] + incl - val;
    if (tid <= NCELL) cellStart[b * CSTRIDE + tid] = excl;
    lhist[tid] = excl;  // only tid reads its own slot until the next barrier
    __syncthreads();
#pragma unroll
    for (int c = 0; c < NPTS / 1024; c++) {
      const int i = c * 1024 + tid;
      const float x = xb[i * 3 + 0];
      const float y = xb[i * 3 + 1];
      const float z = xb[i * 3 + 2];
      int cx, cy, cz;
      cell3(x, y, z, cx, cy, cz);
      const int cid = (cz * GRID + cy) * GRID + cx;
      const int pos = lhist[cid] + atomicAdd(&lfill[cid], 1);
      cellPts[(size_t)b * NPTS + pos] = make_float4(x, y, z, __int_as_float(i));
    }
  } else {
    const int t2 = blockIdx.x - BATCH;
    const int b = t2 >> 8;  // 256 tiles per batch
    const int n0 = (t2 & 255) * 64;
    const float* inb = feat + (size_t)b * NFEAT * NPTS;
    float* outb = featT + (size_t)b * NPTS * NFEAT;
    {
      const int c = tid >> 4;
      const int nq = (tid & 15) * 4;
      const float4 v = *(const float4*)&inb[(size_t)c * NPTS + n0 + nq];
      tile[c][nq + 0] = v.x;
      tile[c][nq + 1] = v.y;
      tile[c][nq + 2] = v.z;
      tile[c][nq + 3] = v.w;
    }
    __syncthreads();
    {
      const int n = tid >> 4;
      const int cq = (tid & 15) * 4;
      float4 v;
      v.x = tile[cq + 0][n];
      v.y = tile[cq + 1][n];
      v.z = tile[cq + 2][n];
      v.w = tile[cq + 3][n];
      *(float4*)&outb[(size_t)(n0 + n) * NFEAT + cq] = v;
    }
  }
}

// ---------------------------------------------------------------------------
// main: changes vs previous round:
//  (1) ZERO __syncthreads — all LDS is per-wave ([w] indexed); waves run
//      fully decoupled with wave_fence() for LDS visibility.
//  (2) conditional bitonic: sort 64 keys when count<=64 (~half of queries),
//      128 otherwise.
//  (3) all 8 feature gathers + 3 coord gathers issued up-front (MLP) before
//      any LDS transpose work.
// ---------------------------------------------------------------------------
__global__ __launch_bounds__(256) void qg_main(
    const float* __restrict__ xyz, const float* __restrict__ new_xyz,
    const float* __restrict__ featT, const float4* __restrict__ cellPts,
    const int* __restrict__ cellStart, float* __restrict__ out) {
  __shared__ int H[4][MAXHIT];    // 2 KB   (per-wave)
  __shared__ int S[4][NS];        // 0.5 KB (per-wave)
  __shared__ float F[4][35][33];  // 18.5 KB; pad 33: 2-way conflicts (free)

  const int w = threadIdx.x >> 6;
  const int lane = threadIdx.x & 63;
  const int query = blockIdx.x * 4 + w;
  const int b = query >> 11;  // / NQ
  const int j = query & (NQ - 1);

  const float* q = new_xyz + ((size_t)b * NQ + j) * 3;
  const float qx = q[0], qy = q[1], qz = q[2];
  const float R2 = (float)(0.1 * 0.1);  // 0x3C23D70A — matches np exactly

  int cx, cy, cz;
  cell3(qx, qy, qz, cx, cy, cz);
  const int* cs = cellStart + b * CSTRIDE;
  const float4* cp = cellPts + (size_t)b * NPTS;

  // ---- preload all 9 row bounds: unconditional clamped loads ----
  const int cxm = max(cx - 1, 0);
  const int cxp = min(cx + 1, GRID - 1);
  int sA[9], eA[9];
#pragma unroll
  for (int r = 0; r < 9; r++) {
    const int dy = r % 3 - 1, dz = r / 3 - 1;
    const int cyy = cy + dy, czz = cz + dz;
    const bool ok = ((unsigned)cyy < GRID) && ((unsigned)czz < GRID);
    const int rowbase = (czz * GRID + cyy) * GRID;
    const int i0 = ok ? rowbase + cxm : 0;
    const int i1 = ok ? rowbase + cxp + 1 : 0;
    const int sv = cs[i0];
    const int ev = cs[i1];
    sA[r] = ok ? sv : 0;
    eA[r] = ok ? ev : 0;
  }

  // ---- prefetch first chunk of every row ----
  float4 P[9];
#pragma unroll
  for (int r = 0; r < 9; r++) P[r] = cp[min(sA[r] + lane, NPTS - 1)];

  // ---- collect all hit indices into the per-wave LDS list ----
  int count = 0;
#pragma unroll
  for (int r = 0; r < 9; r++) {
    const int e = eA[r];
    int i = sA[r] + lane;
    float4 p = P[r];
    while (true) {
      const float dxf = __fsub_rn(qx, p.x);
      const float dyf = __fsub_rn(qy, p.y);
      const float dzf = __fsub_rn(qz, p.z);
      const float d2 =
          __fadd_rn(__fadd_rn(__fmul_rn(dxf, dxf), __fmul_rn(dyf, dyf)),
                    __fmul_rn(dzf, dzf));
      const bool hit = (i < e) && (d2 < R2);
      const unsigned long long m = __ballot(hit);
      if (hit) {
        const int pos = count + prefix_popc(m);
        if (pos < MAXHIT) H[w][pos] = __float_as_int(p.w);  // key = point idx
      }
      count += (int)__popcll(m);
      i += 64;
      if (__ballot(i < e) == 0ull) break;  // uniform: common case exits here
      p = cp[min(i, NPTS - 1)];
    }
  }
  wave_fence();  // H visible within wave

  if (count <= 64) {
    // ---- 64-key register bitonic (taken ~half the time; 21 shuffles) ----
    int v0 = (lane < count) ? H[w][lane] : 0x7fffffff;
#pragma unroll
    for (int k = 2; k <= 64; k <<= 1) {
#pragma unroll
      for (int jj = k >> 1; jj > 0; jj >>= 1) {
        const int o0 = __shfl_xor(v0, jj);
        const bool lower = (lane & jj) == 0;
        const bool up0 = (lane & k) == 0;  // k==64 -> ascending final merge
        v0 = (up0 == lower) ? min(v0, o0) : max(v0, o0);
      }
    }
    const int found = min(count, NS);
    const int fill0 = __shfl(v0, 0);
    if (lane < NS) S[w][lane] = (lane < found) ? v0 : (found ? fill0 : 0);
  } else if (count <= MAXHIT) {
    // ---- 128-key register bitonic (guarded loads, no pre-init) ----
    int v0 = (lane < count) ? H[w][lane] : 0x7fffffff;
    int v1 = (lane + 64 < count) ? H[w][lane + 64] : 0x7fffffff;
#pragma unroll
    for (int k = 2; k <= 128; k <<= 1) {
#pragma unroll
      for (int jj = k >> 1; jj > 0; jj >>= 1) {
        if (jj == 64) {  // only when k==128: cross-register, same lane
          const int lo = min(v0, v1), hi = max(v0, v1);
          v0 = lo;
          v1 = hi;
        } else {
          const int o0 = __shfl_xor(v0, jj);
          const int o1 = __shfl_xor(v1, jj);
          const bool lower = (lane & jj) == 0;
          const bool up0 = (lane & k) == 0;         // element id = lane
          const bool up1 = ((lane + 64) & k) == 0;  // element id = lane+64
          v0 = (up0 == lower) ? min(v0, o0) : max(v0, o0);
          v1 = (up1 == lower) ? min(v1, o1) : max(v1, o1);
        }
      }
    }
    const int found = min(count, NS);
    const int fill0 = __shfl(v0, 0);  // smallest key = first hit idx
    if (lane < NS) S[w][lane] = (lane < found) ? v0 : (found ? fill0 : 0);
  } else {
    // ---- overflow fallback (P ~ 1e-10): exact ordered sequential scan ----
    const float* xb = xyz + (size_t)b * NPTS * 3;
    int cnt2 = 0;
    for (int base = 0; base < NPTS; base += 64) {
      const int i = base + lane;
      const float dxf = __fsub_rn(qx, xb[i * 3 + 0]);
      const float dyf = __fsub_rn(qy, xb[i * 3 + 1]);
      const float dzf = __fsub_rn(qz, xb[i * 3 + 2]);
      const float d2 =
          __fadd_rn(__fadd_rn(__fmul_rn(dxf, dxf), __fmul_rn(dyf, dyf)),
                    __fmul_rn(dzf, dzf));
      const bool hit = d2 < R2;
      const unsigned long long m = __ballot(hit);
      if (hit) {
        const int pos = cnt2 + prefix_popc(m);
        if (pos < NS) S[w][pos] = i;
      }
      cnt2 += (int)__popcll(m);
      if (cnt2 >= NS) break;
    }
    wave_fence();
    const int found = min(cnt2, NS);
    if (lane < NS && lane >= found) S[w][lane] = found ? S[w][0] : 0;
  }
  wave_fence();  // S visible within wave

  // ---- group phase: issue ALL gathers up-front, then LDS transpose ----
  const int r8 = lane >> 3;  // row/channel selector
  const int l8 = lane & 7;   // float4 slot
  const float* fb = featT + (size_t)b * NPTS * NFEAT;
  const float* xb = xyz + (size_t)b * NPTS * 3;
  const size_t ob = ((size_t)b * NCH * NQ + j) * (size_t)NS;

  int gi_t[4];
#pragma unroll
  for (int t = 0; t < 4; t++) gi_t[t] = S[w][t * 8 + r8];
  const int gi3 = (lane < NS) ? S[w][lane] : 0;

  // 8 float4 feature gathers + 3 coord gathers, all in flight together
  float4 g0[4], g1[4];
#pragma unroll
  for (int t = 0; t < 4; t++) {
    g0[t] = *(const float4*)&fb[(size_t)gi_t[t] * NFEAT + l8 * 4];
    g1[t] = *(const float4*)&fb[(size_t)gi_t[t] * NFEAT + 32 + l8 * 4];
  }
  float c0v = 0.f, c1v = 0.f, c2v = 0.f;
  if (lane < NS) {
    // count==0 => S holds 0 => xyz[0]-q, matching the reference's idx=0 pad
    c0v = __fsub_rn(xb[gi3 * 3 + 0], qx);
    c1v = __fsub_rn(xb[gi3 * 3 + 1], qy);
    c2v = __fsub_rn(xb[gi3 * 3 + 2], qz);
  }

  // pass 0: coords -> F rows 0..2, features 0..31 -> F rows 3..34
  if (lane < NS) {
    F[w][0][lane] = c0v;
    F[w][1][lane] = c1v;
    F[w][2][lane] = c2v;
  }
#pragma unroll
  for (int t = 0; t < 4; t++) {
    const int srow = t * 8 + r8;
    F[w][3 + l8 * 4 + 0][srow] = g0[t].x;
    F[w][3 + l8 * 4 + 1][srow] = g0[t].y;
    F[w][3 + l8 * 4 + 2][srow] = g0[t].z;
    F[w][3 + l8 * 4 + 3][srow] = g0[t].w;
  }
  wave_fence();
#pragma unroll
  for (int c0 = 0; c0 < 35; c0 += 8) {
    const int c = c0 + r8;
    if (c < 35) {
      float4 v;
      v.x = F[w][c][l8 * 4 + 0];
      v.y = F[w][c][l8 * 4 + 1];
      v.z = F[w][c][l8 * 4 + 2];
      v.w = F[w][c][l8 * 4 + 3];
      *(float4*)&out[ob + (size_t)c * (NQ * NS) + l8 * 4] = v;
    }
  }
  wave_fence();  // WAR: pass-1 overwrites F (DS in-order per wave, belt+braces)

  // pass 1: features 32..63 -> F rows 0..31; store channels 35..66
#pragma unroll
  for (int t = 0; t < 4; t++) {
    const int srow = t * 8 + r8;
    F[w][l8 * 4 + 0][srow] = g1[t].x;
    F[w][l8 * 4 + 1][srow] = g1[t].y;
    F[w][l8 * 4 + 2][srow] = g1[t].z;
    F[w][l8 * 4 + 3][srow] = g1[t].w;
  }
  wave_fence();
#pragma unroll
  for (int c0 = 0; c0 < 32; c0 += 8) {
    const int r = c0 + r8;
    const int c = 35 + r;
    float4 v;
    v.x = F[w][r][l8 * 4 + 0];
    v.y = F[w][r][l8 * 4 + 1];
    v.z = F[w][r][l8 * 4 + 2];
    v.w = F[w][r][l8 * 4 + 3];
    *(float4*)&out[ob + (size_t)c * (NQ * NS) + l8 * 4] = v;
  }
}

// ---------------------------------------------------------------------------
// Fallback for tiny workspace: direct scan kernel (round-1, known-correct).
// ---------------------------------------------------------------------------
__global__ __launch_bounds__(256) void query_group_direct(
    const float* __restrict__ xyz, const float* __restrict__ new_xyz,
    const float* __restrict__ feat, float* __restrict__ out) {
  __shared__ int sidx[4][NS];
  const int w = threadIdx.x >> 6;
  const int lane = threadIdx.x & 63;
  const int query = blockIdx.x * 4 + w;
  const int b = query >> 11;
  const int j = query & (NQ - 1);
  const float* q = new_xyz + ((size_t)b * NQ + j) * 3;
  const float qx = q[0], qy = q[1], qz = q[2];
  const float* xb = xyz + (size_t)b * NPTS * 3;
  const float R2 = (float)(0.1 * 0.1);
  int count = 0;
  for (int base = 0; base < NPTS; base += 64) {
    const int i = base + lane;
    const float dx = __fsub_rn(qx, xb[i * 3 + 0]);
    const float dy = __fsub_rn(qy, xb[i * 3 + 1]);
    const float dz = __fsub_rn(qz, xb[i * 3 + 2]);
    const float d2 = __fadd_rn(
        __fadd_rn(__fmul_rn(dx, dx), __fmul_rn(dy, dy)), __fmul_rn(dz, dz));
    const bool hit = d2 < R2;
    const unsigned long long m = __ballot(hit);
    if (hit) {
      const int pos = count + prefix_popc(m);
      if (pos < NS) sidx[w][pos] = i;
    }
    count += (int)__popcll(m);
    if (count >= NS) break;
  }
  __syncthreads();
  const int found = count < NS ? count : NS;
  const int fill = (found > 0) ? sidx[w][0] : 0;
  if (lane < NS && lane >= found) sidx[w][lane] = fill;
  __syncthreads();
  const int k = lane & 31;
  const int half = lane >> 5;
  const int gi = sidx[w][k];
  const float px = xb[gi * 3 + 0], py = xb[gi * 3 + 1], pz = xb[gi * 3 + 2];
  const size_t obase = ((size_t)b * NCH * NQ + j) * (size_t)NS + k;
  for (int c = half; c < NCH; c += 2) {
    float v;
    if (c < 3) {
      v = (c == 0) ? __fsub_rn(px, qx)
                   : (c == 1) ? __fsub_rn(py, qy) : __fsub_rn(pz, qz);
    } else {
      v = feat[((size_t)b * NFEAT + (c - 3)) * NPTS + gi];
    }
    out[obase + (size_t)c * (NQ * NS)] = v;
  }
}

extern "C" void kernel_launch(void* const* d_in, const int* in_sizes, int n_in,
                              void* d_out, int out_size, void* d_ws,
                              size_t ws_size, hipStream_t stream) {
  const float* xyz     = (const float*)d_in[0];  // (B, N, 3)
  const float* new_xyz = (const float*)d_in[1];  // (B, NPOINT, 3)
  const float* feat    = (const float*)d_in[2];  // (B, C, N)
  float* out = (float*)d_out;                    // (B, 67, NPOINT, 32)

  const size_t szFeatT  = (size_t)BATCH * NPTS * NFEAT * sizeof(float);  // 16MB
  const size_t szCells  = (size_t)BATCH * NPTS * sizeof(float4);         // 1MB
  const size_t szCStart = (size_t)BATCH * CSTRIDE * sizeof(int);
  const size_t need = szFeatT + szCells + szCStart;

  const int nblocks = (BATCH * NQ) / 4;  // one wave per query

  if (ws_size >= need) {
    char* p = (char*)d_ws;
    float*  featT     = (float*)p;  p += szFeatT;
    float4* cellPts   = (float4*)p; p += szCells;
    int*    cellStart = (int*)p;

    prep_kernel<<<BATCH + BATCH * (NPTS / 64), 1024, 0, stream>>>(
        xyz, feat, featT, cellPts, cellStart);
    qg_main<<<nblocks, 256, 0, stream>>>(xyz, new_xyz, featT, cellPts,
                                         cellStart, out);
  } else {
    query_group_direct<<<nblocks, 256, 0, stream>>>(xyz, new_xyz, feat, out);
  }
}